// Round 2
// baseline (1981.038 us; speedup 1.0000x reference)
//
#include <hip/hip_runtime.h>
#include <hip/hip_bf16.h>
#include <math.h>

// Problem constants (B=2, S=2048, D=1024, H=16, DH=64)
#define Bb 2
#define Ss 2048
#define Dd 1024
#define Hh 16
#define DHh 64

typedef unsigned short u16;
typedef unsigned int u32;

__device__ __forceinline__ u16 fb(float f){
    u32 x = __float_as_uint(f);
    return (u16)((x + 0x7fffu + ((x>>16)&1u)) >> 16);   // RNE bf16
}
__device__ __forceinline__ u32 pack2(float a, float b){
    return (u32)fb(a) | ((u32)fb(b)<<16);
}
__device__ __forceinline__ void unpack8(uint4 v, float* f){
    f[0]=__uint_as_float(v.x<<16); f[1]=__uint_as_float(v.x&0xffff0000u);
    f[2]=__uint_as_float(v.y<<16); f[3]=__uint_as_float(v.y&0xffff0000u);
    f[4]=__uint_as_float(v.z<<16); f[5]=__uint_as_float(v.z&0xffff0000u);
    f[6]=__uint_as_float(v.w<<16); f[7]=__uint_as_float(v.w&0xffff0000u);
}

// ---------------------------------------------------------------------------
// C[M,N] = A[M,K] @ W[N,K]^T + bias.
// ABF16: A is bf16 (ws intermediate) vs fp32 (harness input).
// MODE 0: fp32 row-major store (final output). MODE 1: bf16 split-head store
// to [B,H,S,DH] ws (m = b*S+s, n = h*DH+d).
// 128x128 tile, BK=16, 256 threads, 8x8 micro-tile, fp32 accumulate.
// ---------------------------------------------------------------------------
template<int ABF16, int MODE>
__global__ __launch_bounds__(256) void gemm_at(
    const void* __restrict__ Av, const float* __restrict__ W,
    const float* __restrict__ bias, void* __restrict__ outv,
    int M, int N, int K)
{
    __shared__ float As[16][132];
    __shared__ float Wsh[16][132];
    const int t = threadIdx.x;
    const int ty = t >> 4, tx = t & 15;
    const int bm = blockIdx.x, bn = blockIdx.y;
    const int lr = t >> 1;          // 0..127
    const int lc = (t & 1) * 8;     // 0 or 8
    const float* Wp = W + (size_t)(bn*128 + lr) * K + lc;

    float acc[8][8];
    #pragma unroll
    for (int i=0;i<8;i++)
        #pragma unroll
        for (int j=0;j<8;j++) acc[i][j]=0.f;

    for (int kt=0; kt<K; kt+=16){
        float af[8], wf[8];
        if (ABF16){
            const u16* Ap = (const u16*)Av + (size_t)(bm*128 + lr) * K + lc;
            uint4 av = *(const uint4*)(Ap + kt);
            unpack8(av, af);
        } else {
            const float* Ap = (const float*)Av + (size_t)(bm*128 + lr) * K + lc;
            float4 a0 = *(const float4*)(Ap + kt);
            float4 a1 = *(const float4*)(Ap + kt + 4);
            af[0]=a0.x; af[1]=a0.y; af[2]=a0.z; af[3]=a0.w;
            af[4]=a1.x; af[5]=a1.y; af[6]=a1.z; af[7]=a1.w;
        }
        {
            float4 w0 = *(const float4*)(Wp + kt);
            float4 w1 = *(const float4*)(Wp + kt + 4);
            wf[0]=w0.x; wf[1]=w0.y; wf[2]=w0.z; wf[3]=w0.w;
            wf[4]=w1.x; wf[5]=w1.y; wf[6]=w1.z; wf[7]=w1.w;
        }
        __syncthreads();
        #pragma unroll
        for (int i=0;i<8;i++){ As[lc+i][lr]=af[i]; Wsh[lc+i][lr]=wf[i]; }
        __syncthreads();
        #pragma unroll
        for (int kk=0;kk<16;kk++){
            float4 a0=*(const float4*)&As[kk][ty*8];
            float4 a1=*(const float4*)&As[kk][ty*8+4];
            float4 b0=*(const float4*)&Wsh[kk][tx*8];
            float4 b1=*(const float4*)&Wsh[kk][tx*8+4];
            float a[8]={a0.x,a0.y,a0.z,a0.w,a1.x,a1.y,a1.z,a1.w};
            float c[8]={b0.x,b0.y,b0.z,b0.w,b1.x,b1.y,b1.z,b1.w};
            #pragma unroll
            for (int i=0;i<8;i++)
                #pragma unroll
                for (int j=0;j<8;j++) acc[i][j] = fmaf(a[i], c[j], acc[i][j]);
        }
    }

    const int n0 = bn*128 + tx*8;
    float4 bv0 = *(const float4*)(bias + n0);
    float4 bv1 = *(const float4*)(bias + n0 + 4);
    float bb8[8] = {bv0.x,bv0.y,bv0.z,bv0.w,bv1.x,bv1.y,bv1.z,bv1.w};
    #pragma unroll
    for (int i=0;i<8;i++){
        const int m = bm*128 + ty*8 + i;
        float r[8];
        #pragma unroll
        for (int j=0;j<8;j++) r[j] = acc[i][j] + bb8[j];
        if (MODE==0){
            float* op = (float*)outv + (size_t)m*N + n0;
            *(float4*)op     = make_float4(r[0],r[1],r[2],r[3]);
            *(float4*)(op+4) = make_float4(r[4],r[5],r[6],r[7]);
        } else {
            const int b = m >> 11, s = m & (Ss-1);
            const int h = n0 >> 6, d = n0 & (DHh-1);
            uint4 sv;
            sv.x = pack2(r[0],r[1]); sv.y = pack2(r[2],r[3]);
            sv.z = pack2(r[4],r[5]); sv.w = pack2(r[6],r[7]);
            *(uint4*)((u16*)outv + ((size_t)((b*Hh + h)*Ss + s))*DHh + d) = sv;
        }
    }
}

// ---------------------------------------------------------------------------
// S1: per-row softmax stats (m, l) via online streaming over K tiles.
// Block: 128 q-rows x all 2048 keys for one (b,h). 256 thr, micro 8x4.
// Q, K are bf16 ws intermediates in [B,H,S,DH].
// ---------------------------------------------------------------------------
__global__ __launch_bounds__(256) void attn_stats(
    const u16* __restrict__ Q, const u16* __restrict__ Km,
    const int* __restrict__ mask,
    float* __restrict__ mstat, float* __restrict__ lstat)
{
    __shared__ float Qs[64][132];
    __shared__ float Ks[64][68];
    const int t = threadIdx.x, ty = t>>4, tx = t&15;
    const int qt = blockIdx.x, bh = blockIdx.y;
    const int b = bh >> 4;
    const int qr0 = qt * 128;
    const u16* qb = Q + (size_t)(bh*Ss + qr0)*DHh;
    const u16* kb = Km + (size_t)bh*Ss*DHh;
    const int* mb = mask + (size_t)b*Ss*Ss;

    {   // Q tile 128x64 -> Qs[d][m]
        const int r = t>>1, c0 = (t&1)*32;
        #pragma unroll
        for (int i=0;i<4;i++){
            uint4 v = *(const uint4*)(qb + (size_t)r*DHh + c0 + i*8);
            float f[8]; unpack8(v,f);
            #pragma unroll
            for (int j=0;j<8;j++) Qs[c0+i*8+j][r] = f[j];
        }
    }
    float mt[8], lt[8];
    #pragma unroll
    for (int i=0;i<8;i++){ mt[i]=-INFINITY; lt[i]=0.f; }

    for (int k0=0; k0<Ss; k0+=64){
        __syncthreads();
        {   // K tile 64x64 -> Ks[d][n]
            const int r = t>>2, c0 = (t&3)*16;
            #pragma unroll
            for (int i=0;i<2;i++){
                uint4 v = *(const uint4*)(kb + (size_t)(k0+r)*DHh + c0 + i*8);
                float f[8]; unpack8(v,f);
                #pragma unroll
                for (int j=0;j<8;j++) Ks[c0+i*8+j][r] = f[j];
            }
        }
        __syncthreads();
        float s[8][4];
        #pragma unroll
        for (int i=0;i<8;i++)
            #pragma unroll
            for (int j=0;j<4;j++) s[i][j]=0.f;
        #pragma unroll 8
        for (int d=0;d<64;d++){
            float4 a0=*(const float4*)&Qs[d][ty*8];
            float4 a1=*(const float4*)&Qs[d][ty*8+4];
            float4 c4=*(const float4*)&Ks[d][tx*4];
            float a[8]={a0.x,a0.y,a0.z,a0.w,a1.x,a1.y,a1.z,a1.w};
            float c[4]={c4.x,c4.y,c4.z,c4.w};
            #pragma unroll
            for (int i=0;i<8;i++)
                #pragma unroll
                for (int j=0;j<4;j++) s[i][j]=fmaf(a[i],c[j],s[i][j]);
        }
        #pragma unroll
        for (int i=0;i<8;i++){
            const int qi = qr0 + ty*8 + i;
            int4 mm = *(const int4*)(mb + (size_t)qi*Ss + k0 + tx*4);
            float sv[4];
            sv[0] = mm.x ? s[i][0]*0.125f : -INFINITY;
            sv[1] = mm.y ? s[i][1]*0.125f : -INFINITY;
            sv[2] = mm.z ? s[i][2]*0.125f : -INFINITY;
            sv[3] = mm.w ? s[i][3]*0.125f : -INFINITY;
            float tm = fmaxf(fmaxf(sv[0],sv[1]), fmaxf(sv[2],sv[3]));
            if (tm > -INFINITY){
                float mn = fmaxf(mt[i], tm);
                float l = lt[i] * __expf(mt[i]-mn);
                l += __expf(sv[0]-mn); l += __expf(sv[1]-mn);
                l += __expf(sv[2]-mn); l += __expf(sv[3]-mn);
                mt[i]=mn; lt[i]=l;
            }
        }
    }
    __syncthreads();
    float* red = &Ks[0][0];   // reuse: 128*16*2 = 4096 floats <= 64*68
    #pragma unroll
    for (int i=0;i<8;i++){
        const int rl = ty*8+i;
        red[(rl*16+tx)*2+0] = mt[i];
        red[(rl*16+tx)*2+1] = lt[i];
    }
    __syncthreads();
    if (t < 128){
        float m = -INFINITY;
        #pragma unroll
        for (int x=0;x<16;x++) m = fmaxf(m, red[(t*16+x)*2]);
        float l = 0.f;
        if (m > -INFINITY){
            #pragma unroll
            for (int x=0;x<16;x++) l += red[(t*16+x)*2+1]*__expf(red[(t*16+x)*2]-m);
        }
        mstat[(size_t)bh*Ss + qr0 + t] = m;
        lstat[(size_t)bh*Ss + qr0 + t] = l;
    }
}

// ---------------------------------------------------------------------------
// S2: recompute scores, normalize with (m,l), write fp32 weights to d_out.
// ---------------------------------------------------------------------------
__global__ __launch_bounds__(256) void attn_weights(
    const u16* __restrict__ Q, const u16* __restrict__ Km,
    const int* __restrict__ mask,
    const float* __restrict__ mstat, const float* __restrict__ lstat,
    float* __restrict__ wout)
{
    __shared__ float Qs[64][132];
    __shared__ float Ks[64][68];
    const int t = threadIdx.x, ty = t>>4, tx = t&15;
    const int qt = blockIdx.x, bh = blockIdx.y;
    const int b = bh >> 4;
    const int qr0 = qt * 128;
    const u16* qb = Q + (size_t)(bh*Ss + qr0)*DHh;
    const u16* kb = Km + (size_t)bh*Ss*DHh;
    const int* mb = mask + (size_t)b*Ss*Ss;

    {   const int r = t>>1, c0 = (t&1)*32;
        #pragma unroll
        for (int i=0;i<4;i++){
            uint4 v = *(const uint4*)(qb + (size_t)r*DHh + c0 + i*8);
            float f[8]; unpack8(v,f);
            #pragma unroll
            for (int j=0;j<8;j++) Qs[c0+i*8+j][r] = f[j];
        }
    }
    float mr[8], li[8];
    #pragma unroll
    for (int i=0;i<8;i++){
        const int qi = qr0 + ty*8 + i;
        mr[i] = mstat[(size_t)bh*Ss + qi];
        float l = lstat[(size_t)bh*Ss + qi];
        li[i] = l > 0.f ? 1.f/l : 0.f;
    }

    for (int k0=0; k0<Ss; k0+=64){
        __syncthreads();
        {   const int r = t>>2, c0 = (t&3)*16;
            #pragma unroll
            for (int i=0;i<2;i++){
                uint4 v = *(const uint4*)(kb + (size_t)(k0+r)*DHh + c0 + i*8);
                float f[8]; unpack8(v,f);
                #pragma unroll
                for (int j=0;j<8;j++) Ks[c0+i*8+j][r] = f[j];
            }
        }
        __syncthreads();
        float s[8][4];
        #pragma unroll
        for (int i=0;i<8;i++)
            #pragma unroll
            for (int j=0;j<4;j++) s[i][j]=0.f;
        #pragma unroll 8
        for (int d=0;d<64;d++){
            float4 a0=*(const float4*)&Qs[d][ty*8];
            float4 a1=*(const float4*)&Qs[d][ty*8+4];
            float4 c4=*(const float4*)&Ks[d][tx*4];
            float a[8]={a0.x,a0.y,a0.z,a0.w,a1.x,a1.y,a1.z,a1.w};
            float c[4]={c4.x,c4.y,c4.z,c4.w};
            #pragma unroll
            for (int i=0;i<8;i++)
                #pragma unroll
                for (int j=0;j<4;j++) s[i][j]=fmaf(a[i],c[j],s[i][j]);
        }
        #pragma unroll
        for (int i=0;i<8;i++){
            const int qi = qr0 + ty*8 + i;
            int4 mm = *(const int4*)(mb + (size_t)qi*Ss + k0 + tx*4);
            float w0 = mm.x ? __expf(s[i][0]*0.125f - mr[i])*li[i] : 0.f;
            float w1 = mm.y ? __expf(s[i][1]*0.125f - mr[i])*li[i] : 0.f;
            float w2 = mm.z ? __expf(s[i][2]*0.125f - mr[i])*li[i] : 0.f;
            float w3 = mm.w ? __expf(s[i][3]*0.125f - mr[i])*li[i] : 0.f;
            *(float4*)(wout + ((size_t)bh*Ss + qi)*Ss + k0 + tx*4) =
                make_float4(w0,w1,w2,w3);
        }
    }
}

// ---------------------------------------------------------------------------
// PV: attn[b,s,h*DH+d] = sum_j weights[b,h,s,j] * vs[b,h,j,d]
// Weights fp32 (from d_out), V bf16 (ws), attn bf16 (ws).
// ---------------------------------------------------------------------------
__global__ __launch_bounds__(256) void attn_pv(
    const float* __restrict__ Wg, const u16* __restrict__ V,
    u16* __restrict__ attn)
{
    __shared__ float Wt[64][132];
    __shared__ float Vt[64][68];
    const int t=threadIdx.x, ty=t>>4, tx=t&15;
    const int qt=blockIdx.x, bh=blockIdx.y;
    const int b=bh>>4, h=bh&15;
    const int qr0=qt*128;
    const float* wb = Wg + ((size_t)bh*Ss + qr0)*Ss;
    const u16* vb = V + (size_t)bh*Ss*DHh;
    float acc[8][4];
    #pragma unroll
    for (int i=0;i<8;i++)
        #pragma unroll
        for (int j=0;j<4;j++) acc[i][j]=0.f;

    for (int j0=0;j0<Ss;j0+=64){
        __syncthreads();
        {   // weights tile 128x64 fp32 -> Wt[j][q]
            const int r=t>>1, c0=(t&1)*32;
            #pragma unroll
            for (int i=0;i<8;i++){
                float4 v4=*(const float4*)(wb + (size_t)r*Ss + j0 + c0 + i*4);
                Wt[c0+i*4+0][r]=v4.x; Wt[c0+i*4+1][r]=v4.y;
                Wt[c0+i*4+2][r]=v4.z; Wt[c0+i*4+3][r]=v4.w;
            }
        }
        {   // V tile 64x64 bf16 -> Vt[j][d]
            const int r=t>>2, c0=(t&3)*16;
            #pragma unroll
            for (int i=0;i<2;i++){
                uint4 v=*(const uint4*)(vb + (size_t)(j0+r)*DHh + c0+i*8);
                float f[8]; unpack8(v,f);
                #pragma unroll
                for (int j=0;j<8;j++) Vt[r][c0+i*8+j]=f[j];
            }
        }
        __syncthreads();
        #pragma unroll 8
        for (int kj=0;kj<64;kj++){
            float4 a0=*(const float4*)&Wt[kj][ty*8];
            float4 a1=*(const float4*)&Wt[kj][ty*8+4];
            float4 c4=*(const float4*)&Vt[kj][tx*4];
            float a[8]={a0.x,a0.y,a0.z,a0.w,a1.x,a1.y,a1.z,a1.w};
            float c[4]={c4.x,c4.y,c4.z,c4.w};
            #pragma unroll
            for (int i=0;i<8;i++)
                #pragma unroll
                for (int j=0;j<4;j++) acc[i][j]=fmaf(a[i],c[j],acc[i][j]);
        }
    }
    #pragma unroll
    for (int i=0;i<8;i++){
        const int s = qr0 + ty*8 + i;
        uint2 sv; sv.x=pack2(acc[i][0],acc[i][1]); sv.y=pack2(acc[i][2],acc[i][3]);
        *(uint2*)(attn + ((size_t)(b*Ss+s))*Dd + h*DHh + tx*4) = sv;
    }
}

// ---------------------------------------------------------------------------
extern "C" void kernel_launch(void* const* d_in, const int* in_sizes, int n_in,
                              void* d_out, int out_size, void* d_ws, size_t ws_size,
                              hipStream_t stream) {
    const float* q      = (const float*)d_in[0];
    const float* k      = (const float*)d_in[1];
    const float* v      = (const float*)d_in[2];
    const int*   mask   = (const int*)d_in[3];
    const float* wq_w   = (const float*)d_in[4];
    const float* wq_b   = (const float*)d_in[5];
    const float* wk_w   = (const float*)d_in[6];
    const float* wk_b   = (const float*)d_in[7];
    const float* wv_w   = (const float*)d_in[8];
    const float* wv_b   = (const float*)d_in[9];
    const float* dense_w= (const float*)d_in[10];
    const float* dense_b= (const float*)d_in[11];

    float* out  = (float*)d_out;                    // [B,S,D] fp32
    float* wout = out + (size_t)Bb*Ss*Dd;           // [B,H,S,S] fp32

    // workspace layout (bf16 intermediates, ~32.5 MB total)
    u16* qs   = (u16*)d_ws;                         // [B,H,S,DH]
    u16* ksb  = qs  + (size_t)Bb*Hh*Ss*DHh;
    u16* vsb  = ksb + (size_t)Bb*Hh*Ss*DHh;
    u16* attn = vsb + (size_t)Bb*Hh*Ss*DHh;         // [B,S,D]
    float* mstat = (float*)(attn + (size_t)Bb*Ss*Dd);
    float* lstat = mstat + (size_t)Bb*Hh*Ss;

    const int M = Bb*Ss, N = Dd, K = Dd;
    dim3 gg(M/128, N/128), bb(256);
    gemm_at<0,1><<<gg, bb, 0, stream>>>(q, wq_w, wq_b, qs,  M, N, K);
    gemm_at<0,1><<<gg, bb, 0, stream>>>(k, wk_w, wk_b, ksb, M, N, K);
    gemm_at<0,1><<<gg, bb, 0, stream>>>(v, wv_w, wv_b, vsb, M, N, K);

    dim3 ga(Ss/128, Bb*Hh);
    attn_stats  <<<ga, bb, 0, stream>>>(qs, ksb, mask, mstat, lstat);
    attn_weights<<<ga, bb, 0, stream>>>(qs, ksb, mask, mstat, lstat, wout);
    attn_pv     <<<ga, bb, 0, stream>>>(wout, vsb, attn);

    gemm_at<1,0><<<gg, bb, 0, stream>>>(attn, dense_w, dense_b, out, M, N, K);
}